// Round 9
// baseline (4363.667 us; speedup 1.0000x reference)
//
#include <hip/hip_runtime.h>

// LSTM: N=64, T=1024, D=512, H=512. out (N,T,H) fp32 = h_{t+1} for t=0..T-1.
//
// Persistent kernel, 128 wgs x 256 thr (R7 structure - proven 3.09ms).
// grid = 32 col-groups x 4 row-groups; each wave owns one gate's 16 a-cols,
// K=1024, fp16 B persistent in VGPRs. h transport: self-announcing tagged
// u32 words (fp16 bits<<16 | gen tag), 2-slot ring, fire-and-forget.
//
// R9 changes (R8 regressed via occupancy error: 512-thr wgs on 64 CUs
// doubled per-CU compute; reverted to R7, two targeted deltas):
//   1. SELECTIVE RE-POLL (R8's good piece): retry rounds reload only
//      words whose tag hasn't matched. R7 reloaded all 32 u64 each round
//      = ~2MB/round across the grid = ~10TB/s of self-inflicted MALL
//      poll traffic. Now steady-state retries are 1-2 loads.
//   2. XCD SWIZZLE: bid -> (rg,cg) s.t. each row-group's 32 wgs sit on
//      2 XCDs (assumes round-robin bid%8 -> XCD; wrong assumption =
//      neutral). Was: every XCD streams ALL of x (8 x 128MB = 1.02GB =
//      observed FETCH). Now each XCD streams its rg's 32MB -> ~0.3GB,
//      less fabric congestion under the h exchange.

#define TT 1024
#define NB 64
#define DD 512
#define HH 512
#define XROW 520           // 512 + 8 pad (elems)
#define NBHH (NB * HH)
#define TTDD (TT * DD)

typedef _Float16 half8 __attribute__((ext_vector_type(8)));
typedef _Float16 half4 __attribute__((ext_vector_type(4)));
typedef float floatx4 __attribute__((ext_vector_type(4)));
typedef unsigned long long u64;
typedef unsigned int u32;
typedef unsigned short u16;

#define AQ __ATOMIC_RELAXED
#define SC __HIP_MEMORY_SCOPE_AGENT

// Fill both ring slots with tag 0xFFFF (matches no generation).
__global__ void init_ws_kernel(u64* hq) {
    hq[blockIdx.x * 256 + threadIdx.x] = 0x0000FFFF0000FFFFULL;  // 32768 u64
}

__device__ __forceinline__ void barrier_lgkm() {
    asm volatile("s_waitcnt lgkmcnt(0)" ::: "memory");
    __builtin_amdgcn_s_barrier();
    asm volatile("" ::: "memory");
}

#define MFMA16(A, B, C) __builtin_amdgcn_mfma_f32_16x16x32_f16((A), (B), (C), 0, 0, 0)

__global__ __launch_bounds__(256, 1) void lstm_persist(
    const float* __restrict__ x, const float* __restrict__ h0,
    const float* __restrict__ Wx, const float* __restrict__ Wh,
    const float* __restrict__ b, float* __restrict__ out,
    u64* __restrict__ hq)
{
    const int tid  = threadIdx.x;
    const int lane = tid & 63;
    const int wave = tid >> 6;          // 0..3 = gate (i,f,o,g)
    // XCD swizzle: xcd = bid&7 (assumed round-robin), k = bid>>3 in 0..15.
    // rg = xcd>>1 (2 XCDs per row-group), cg = (k<<1)|(xcd&1) in 0..31.
    const int bid  = blockIdx.x;
    const int rg   = (bid & 7) >> 1;    // batch rows rg*16..+15
    const int cg   = ((bid >> 3) << 1) | (bid & 1);   // h-cols cg*16..+15
    const int row0 = rg << 4;

    __shared__ __align__(16) _Float16 xbuf[2][16 * XROW];  // x_t / x_{t+1}
    __shared__ __align__(16) _Float16 hlds[16 * XROW];     // h_t rows (fp16)
    __shared__ float gatebuf[4 * 272];                     // 4 gates x (16 x 17)
    __shared__ float houts[2][128];                        // rows 0-7 hv handoff

    // ---- persistent B fragments: this wave's 16 a-cols, K=1024 ----
    const int bcol = (wave << 9) + (cg << 4) + (lane & 15);
    const int kq   = (lane >> 4) << 3;
    half8 bfrag[32];
#pragma unroll
    for (int kt = 0; kt < 16; ++kt)
#pragma unroll
        for (int j = 0; j < 8; ++j)
            bfrag[kt][j] = (_Float16)Wx[(size_t)((kt << 5) + kq + j) * 2048 + bcol];
#pragma unroll
    for (int kt = 16; kt < 32; ++kt)
#pragma unroll
        for (int j = 0; j < 8; ++j)
            bfrag[kt][j] = (_Float16)Wh[(size_t)((kt << 5) + kq + j - 512) * 2048 + bcol];

    // ---- per-thread output element mapping ----
    const int tr = tid >> 4;            // 0..15
    const int tc = tid & 15;
    const int gn = row0 + tr;           // global batch row
    const int gh = (cg << 4) + tc;      // global h col
    const float bi = b[0 * 512 + gh];
    const float bf = b[1 * 512 + gh];
    const float bo = b[2 * 512 + gh];
    const float bg = b[3 * 512 + gh];
    float c_state = 0.f;

    const int r2 = tid >> 7;            // prologue x-staging helpers
    const int d4 = tid & 127;
    const int arow = (lane & 15) * XROW + kq;

    // w23 x-pipeline mapping: 128 threads, 16 rows x 8 thr, 16 float4 each
    const int lt  = tid & 127;
    const int xr  = lt >> 3;            // 0..15
    const int xc8 = lt & 7;             // 0..7

    // ---- prologue: stage x_0 -> xbuf[0]; h0 -> ring slot 0 (gen 0) ----
#pragma unroll
    for (int i = 0; i < 8; ++i) {
        int r = (i << 1) + r2;
        float4 xv = ((const float4*)(x + (size_t)(row0 + r) * TTDD))[d4];
        half4 hc;
        hc.x = (_Float16)xv.x; hc.y = (_Float16)xv.y;
        hc.z = (_Float16)xv.z; hc.w = (_Float16)xv.w;
        *(half4*)&xbuf[0][r * XROW + (d4 << 2)] = hc;
    }
    {
        float hv0 = h0[(size_t)gn * HH + gh];
        float pn  = __shfl_down(hv0, 1);
        if ((tc & 1) == 0) {
            _Float16 f0 = (_Float16)hv0, f1 = (_Float16)pn;
            u16 b0, b1;
            __builtin_memcpy(&b0, &f0, 2); __builtin_memcpy(&b1, &f1, 2);
            const u32 wtag = 0xB000u;   // gen 0: slot 0, tag bit 0
            u32 lo = ((u32)b0 << 16) | wtag;
            u32 hi = ((u32)b1 << 16) | wtag;
            u64 v = (u64)lo | ((u64)hi << 32);
            __hip_atomic_store(hq + (size_t)gn * 256 + (gh >> 1), v, AQ, SC);
        }
    }
    barrier_lgkm();   // xbuf[0] visible

    for (int t = 0; t < TT; ++t) {
        const bool havex = (t + 1 < TT);

        // ---- 1. w23: issue x_{t+1} loads (held in regs through the step) ----
        float4 xvv[16];
        if (wave >= 2 && havex) {
            const float4* xsrc = (const float4*)(x + (size_t)(row0 + xr) * TTDD
                                                 + (size_t)(t + 1) * DD);
#pragma unroll
            for (int j = 0; j < 16; ++j)
                xvv[j] = xsrc[xc8 + (j << 3)];
        }

        // ---- 2. x-part MFMA from xbuf[t&1] (LDS only, all waves) ----
        floatx4 acc0 = {0.f, 0.f, 0.f, 0.f};
        floatx4 acc1 = {0.f, 0.f, 0.f, 0.f};
        const _Float16* xa = xbuf[t & 1];
#pragma unroll
        for (int kt = 0; kt < 16; kt += 2) {
            half8 a0 = *(const half8*)&xa[arow + (kt << 5)];
            half8 a1 = *(const half8*)&xa[arow + ((kt + 1) << 5)];
            acc0 = MFMA16(a0, bfrag[kt],     acc0);
            acc1 = MFMA16(a1, bfrag[kt + 1], acc1);
        }

        // ---- 3. w01: selective poll of own 32 tagged u64; stage to hlds ----
        if (wave < 2) {
            const int pr = tid >> 3;    // 0..15 (tile row)
            const int pc = tid & 7;     // 0..7
            const u64 wantp = ((u64)(0xB000u | ((u32)(t >> 1) & 1u)))
                              * 0x0000000100000001ULL;
            const u64* src = hq + (size_t)(t & 1) * (NBHH / 2)
                           + (size_t)(row0 + pr) * 256 + pc;
            u64 w[32];
            u32 rdy = 0;
            do {
#pragma unroll
                for (int j = 0; j < 32; ++j)
                    if (!((rdy >> j) & 1u))
                        w[j] = __hip_atomic_load(src + (j << 3), AQ, SC);
#pragma unroll
                for (int j = 0; j < 32; ++j)
                    if (!((rdy >> j) & 1u)
                        && ((w[j] ^ wantp) & 0x0000FFFF0000FFFFULL) == 0)
                        rdy |= 1u << j;
            } while (rdy != 0xFFFFFFFFu);
            u32* dst = (u32*)hlds + pr * 260 + pc;
#pragma unroll
            for (int j = 0; j < 32; ++j) {
                u32 lo = (u32)w[j] >> 16;
                u32 hi = (u32)(w[j] >> 32) & 0xFFFF0000u;
                dst[j << 3] = lo | hi;      // cols 2W, 2W+1 (W = pc+8j)
            }
        }
        barrier_lgkm();   // A: h tile staged

        // ---- 4. h-part MFMA (all waves) ----
#pragma unroll
        for (int kt = 0; kt < 16; kt += 2) {
            half8 a0 = *(const half8*)&hlds[arow + (kt << 5)];
            half8 a1 = *(const half8*)&hlds[arow + ((kt + 1) << 5)];
            acc0 = MFMA16(a0, bfrag[16 + kt],     acc0);
            acc1 = MFMA16(a1, bfrag[16 + kt + 1], acc1);
        }
        floatx4 acc = acc0 + acc1;

        // ---- 5. gate exchange through LDS ----
        {
            const int ccol = lane & 15;
            const int crow = (lane >> 4) << 2;
#pragma unroll
            for (int v = 0; v < 4; ++v)
                gatebuf[wave * 272 + (crow + v) * 17 + ccol] = acc[v];
        }

        // ---- 6. w23: handed out-stores (t-1, rows 0-7); cvt x_{t+1} -> LDS ----
        if (wave >= 2) {
            if (t > 0) {
                float hvp = houts[(t - 1) & 1][lt];
                out[(size_t)(row0 + (lt >> 4)) * (TT * HH) + (size_t)(t - 1) * HH
                    + (cg << 4) + (lt & 15)] = hvp;
            }
            if (havex) {
                _Float16* xd = xbuf[(t + 1) & 1] + xr * XROW;
                half4 hc;
#pragma unroll
                for (int j = 0; j < 16; ++j) {
                    float4 v = xvv[j];
                    hc.x = (_Float16)v.x; hc.y = (_Float16)v.y;
                    hc.z = (_Float16)v.z; hc.w = (_Float16)v.w;
                    *(half4*)&xd[(xc8 + (j << 3)) << 2] = hc;
                }
            }
        }
        barrier_lgkm();   // B: gatebuf + xbuf[(t+1)&1] ready

        // ---- 7. epilogue (all threads): cell math; tagged h-store ----
        {
            const int gidx = tr * 17 + tc;
            float ai = gatebuf[0 * 272 + gidx] + bi;
            float af = gatebuf[1 * 272 + gidx] + bf;
            float ao = gatebuf[2 * 272 + gidx] + bo;
            float ag = gatebuf[3 * 272 + gidx] + bg;
            float ig = 1.f / (1.f + __expf(-ai));
            float fg = 1.f / (1.f + __expf(-af));
            float og = 1.f / (1.f + __expf(-ao));
            float gg = 2.f / (1.f + __expf(-2.f * ag)) - 1.f;   // tanh
            c_state = fg * c_state + ig * gg;
            float hv = og * (2.f / (1.f + __expf(-2.f * c_state)) - 1.f);

            float pn = __shfl_down(hv, 1);
            if ((tc & 1) == 0) {
                _Float16 f0 = (_Float16)hv, f1 = (_Float16)pn;
                u16 b0, b1;
                __builtin_memcpy(&b0, &f0, 2); __builtin_memcpy(&b1, &f1, 2);
                const u32 wtag = 0xB000u | ((u32)((t + 1) >> 1) & 1u);
                u32 lo = ((u32)b0 << 16) | wtag;
                u32 hi = ((u32)b1 << 16) | wtag;
                u64 v = (u64)lo | ((u64)hi << 32);
                __hip_atomic_store(hq + (size_t)((t + 1) & 1) * (NBHH / 2)
                                   + (size_t)gn * 256 + (gh >> 1), v, AQ, SC);
            }
            // out: w01 hand over via LDS (w23 stores next step); w23 direct.
            if (wave < 2) houts[t & 1][tid] = hv;
            else out[(size_t)gn * (TT * HH) + (size_t)t * HH + gh] = hv;
        }
        // no barrier here: houts(t) read at t+1 after A; gatebuf rewritten
        // at t+1 after A; hlds restaged pre-A(t+1), readers done pre-B(t).
    }

    // ---- tail: flush handed rows for t = TT-1 ----
    barrier_lgkm();
    if (wave >= 2) {
        float hvp = houts[(TT - 1) & 1][lt];
        out[(size_t)(row0 + (lt >> 4)) * (TT * HH) + (size_t)(TT - 1) * HH
            + (cg << 4) + (lt & 15)] = hvp;
    }
}

extern "C" void kernel_launch(void* const* d_in, const int* in_sizes, int n_in,
                              void* d_out, int out_size, void* d_ws, size_t ws_size,
                              hipStream_t stream) {
    const float* x  = (const float*)d_in[0];
    const float* h0 = (const float*)d_in[1];
    const float* Wx = (const float*)d_in[2];
    const float* Wh = (const float*)d_in[3];
    const float* b  = (const float*)d_in[4];
    float* out = (float*)d_out;

    u64* hq = (u64*)d_ws;   // 2 slots x 64 x 512 x u32 = 256 KB

    init_ws_kernel<<<128, 256, 0, stream>>>(hq);
    lstm_persist<<<dim3(128), dim3(256), 0, stream>>>(x, h0, Wx, Wh, b, out, hq);
}

// Round 10
// 3113.169 us; speedup vs baseline: 1.4017x; 1.4017x over previous
//
#include <hip/hip_runtime.h>

// LSTM: N=64, T=1024, D=512, H=512. out (N,T,H) fp32 = h_{t+1} for t=0..T-1.
//
// Persistent kernel, 128 wgs x 256 thr (EXACT R7 structure, 3.09ms proven).
// grid = 32 col-groups x 4 row-groups; each wave owns one gate's 16 a-cols,
// K=1024, fp16 B persistent in VGPRs. h transport: self-announcing tagged
// u32 words (fp16 bits<<16 | gen tag), 2-slot ring, fire-and-forget.
// Full (non-selective) re-poll; NO xcd swizzle (R9 ablation: swizzle cut
// FETCH 1.06GB->0.30GB but dur regressed -> x-fetch not on critical path).
//
// R10 single change: FRAGMENT-LINEAR LDS layout for xbuf/hlds.
//   off(row,k) = (k>>5)*512 + ((k&31)>>3)*128 + row*8 + (k&7)   [elems]
//   MFMA A-frag read (lane l, kt): off = kt*512 + (l>>4)*128 + (l&15)*8
//   -> 64 lanes x contiguous 16B = canonical conflict-free b128 pattern.
//   R7's row-major tiles (1040B row stride) made every A-read 2-way
//   aliased: SQ_LDS_BANK_CONFLICT 1.09e8 ~= 830 serialized cy/wg/step.
//   Staging writes are remapped (2-4-way, write-side only, fewer ops).

#define TT 1024
#define NB 64
#define DD 512
#define HH 512
#define NBHH (NB * HH)
#define TTDD (TT * DD)

typedef _Float16 half8 __attribute__((ext_vector_type(8)));
typedef _Float16 half4 __attribute__((ext_vector_type(4)));
typedef float floatx4 __attribute__((ext_vector_type(4)));
typedef unsigned long long u64;
typedef unsigned int u32;
typedef unsigned short u16;

#define AQ __ATOMIC_RELAXED
#define SC __HIP_MEMORY_SCOPE_AGENT

// fragment-linear offset (elems) for a 16-row x 512-k fp16 tile
__device__ __forceinline__ int foff(int row, int k) {
    return (k >> 5) * 512 + ((k & 31) >> 3) * 128 + row * 8 + (k & 7);
}

// Fill both ring slots with tag 0xFFFF (matches no generation).
__global__ void init_ws_kernel(u64* hq) {
    hq[blockIdx.x * 256 + threadIdx.x] = 0x0000FFFF0000FFFFULL;  // 32768 u64
}

__device__ __forceinline__ void barrier_lgkm() {
    asm volatile("s_waitcnt lgkmcnt(0)" ::: "memory");
    __builtin_amdgcn_s_barrier();
    asm volatile("" ::: "memory");
}

#define MFMA16(A, B, C) __builtin_amdgcn_mfma_f32_16x16x32_f16((A), (B), (C), 0, 0, 0)

__global__ __launch_bounds__(256, 1) void lstm_persist(
    const float* __restrict__ x, const float* __restrict__ h0,
    const float* __restrict__ Wx, const float* __restrict__ Wh,
    const float* __restrict__ b, float* __restrict__ out,
    u64* __restrict__ hq)
{
    const int tid  = threadIdx.x;
    const int lane = tid & 63;
    const int wave = tid >> 6;          // 0..3 = gate (i,f,o,g)
    const int cg   = blockIdx.x & 31;   // h-cols cg*16..+15
    const int rg   = blockIdx.x >> 5;   // batch rows rg*16..+15
    const int row0 = rg << 4;

    __shared__ __align__(16) _Float16 xbuf[2][16 * 512];   // fragment-linear
    __shared__ __align__(16) _Float16 hlds[16 * 512];      // fragment-linear
    __shared__ float gatebuf[4 * 272];                     // 4 gates x (16 x 17)
    __shared__ float houts[2][128];                        // rows 0-7 hv handoff

    // ---- persistent B fragments: this wave's 16 a-cols, K=1024 ----
    const int bcol = (wave << 9) + (cg << 4) + (lane & 15);
    const int kq   = (lane >> 4) << 3;
    half8 bfrag[32];
#pragma unroll
    for (int kt = 0; kt < 16; ++kt)
#pragma unroll
        for (int j = 0; j < 8; ++j)
            bfrag[kt][j] = (_Float16)Wx[(size_t)((kt << 5) + kq + j) * 2048 + bcol];
#pragma unroll
    for (int kt = 16; kt < 32; ++kt)
#pragma unroll
        for (int j = 0; j < 8; ++j)
            bfrag[kt][j] = (_Float16)Wh[(size_t)((kt << 5) + kq + j - 512) * 2048 + bcol];

    // ---- per-thread output element mapping ----
    const int tr = tid >> 4;            // 0..15
    const int tc = tid & 15;
    const int gn = row0 + tr;           // global batch row
    const int gh = (cg << 4) + tc;      // global h col
    const float bi = b[0 * 512 + gh];
    const float bf = b[1 * 512 + gh];
    const float bo = b[2 * 512 + gh];
    const float bg = b[3 * 512 + gh];
    float c_state = 0.f;

    // MFMA A-frag base: lane-linear contiguous 16B -> conflict-free b128
    const int fragbase = ((lane >> 4) << 7) + ((lane & 15) << 3);

    // w23 x-pipeline mapping: 128 threads, 16 rows x 8 thr, 16 float4 each
    const int lt  = tid & 127;
    const int xr  = lt >> 3;            // 0..15
    const int xc8 = lt & 7;             // 0..7

    // ---- prologue: stage x_0 -> xbuf[0]; h0 -> ring slot 0 (gen 0) ----
    {
        const int prow = tid >> 4;      // 0..15
        const int pc16 = tid & 15;      // 0..15
        const float4* xs = (const float4*)(x + (size_t)(row0 + prow) * TTDD);
#pragma unroll
        for (int j = 0; j < 8; ++j) {
            int c = pc16 + (j << 4);    // float4 slot 0..127
            float4 v = xs[c];
            half4 hc;
            hc.x = (_Float16)v.x; hc.y = (_Float16)v.y;
            hc.z = (_Float16)v.z; hc.w = (_Float16)v.w;
            *(half4*)&xbuf[0][foff(prow, c << 2)] = hc;
        }
    }
    {
        float hv0 = h0[(size_t)gn * HH + gh];
        float pn  = __shfl_down(hv0, 1);
        if ((tc & 1) == 0) {
            _Float16 f0 = (_Float16)hv0, f1 = (_Float16)pn;
            u16 b0, b1;
            __builtin_memcpy(&b0, &f0, 2); __builtin_memcpy(&b1, &f1, 2);
            const u32 wtag = 0xB000u;   // gen 0: slot 0, tag bit 0
            u32 lo = ((u32)b0 << 16) | wtag;
            u32 hi = ((u32)b1 << 16) | wtag;
            u64 v = (u64)lo | ((u64)hi << 32);
            __hip_atomic_store(hq + (size_t)gn * 256 + (gh >> 1), v, AQ, SC);
        }
    }
    barrier_lgkm();   // xbuf[0] visible

    for (int t = 0; t < TT; ++t) {
        const bool havex = (t + 1 < TT);

        // ---- 1. w23: issue x_{t+1} loads (held in regs through the step) ----
        float4 xvv[16];
        if (wave >= 2 && havex) {
            const float4* xsrc = (const float4*)(x + (size_t)(row0 + xr) * TTDD
                                                 + (size_t)(t + 1) * DD);
#pragma unroll
            for (int j = 0; j < 16; ++j)
                xvv[j] = xsrc[xc8 + (j << 3)];
        }

        // ---- 2. x-part MFMA from xbuf[t&1] (LDS only, all waves) ----
        floatx4 acc0 = {0.f, 0.f, 0.f, 0.f};
        floatx4 acc1 = {0.f, 0.f, 0.f, 0.f};
        const _Float16* xa = xbuf[t & 1];
#pragma unroll
        for (int kt = 0; kt < 16; kt += 2) {
            half8 a0 = *(const half8*)&xa[fragbase + (kt << 9)];
            half8 a1 = *(const half8*)&xa[fragbase + ((kt + 1) << 9)];
            acc0 = MFMA16(a0, bfrag[kt],     acc0);
            acc1 = MFMA16(a1, bfrag[kt + 1], acc1);
        }

        // ---- 3. w01: full poll of own 32 tagged u64; stage to hlds ----
        if (wave < 2) {
            const int pr = tid >> 3;    // 0..15 (tile row)
            const int pc = tid & 7;     // 0..7
            const u64 wantp = ((u64)(0xB000u | ((u32)(t >> 1) & 1u)))
                              * 0x0000000100000001ULL;
            const u64* src = hq + (size_t)(t & 1) * (NBHH / 2)
                           + (size_t)(row0 + pr) * 256 + pc;
            u64 w[32];
            bool ok;
            do {
#pragma unroll
                for (int j = 0; j < 32; ++j)
                    w[j] = __hip_atomic_load(src + (j << 3), AQ, SC);
                u64 chk = 0;
#pragma unroll
                for (int j = 0; j < 32; ++j)
                    chk |= (w[j] ^ wantp) & 0x0000FFFF0000FFFFULL;
                ok = (chk == 0);
            } while (!ok);
#pragma unroll
            for (int j = 0; j < 32; ++j) {
                u32 lo = (u32)w[j] >> 16;
                u32 hi = (u32)(w[j] >> 32) & 0xFFFF0000u;
                int k = (pc + (j << 3)) << 1;           // cols k, k+1
                *(u32*)&hlds[foff(pr, k)] = lo | hi;
            }
        }
        barrier_lgkm();   // A: h tile staged

        // ---- 4. h-part MFMA (all waves) ----
#pragma unroll
        for (int kt = 0; kt < 16; kt += 2) {
            half8 a0 = *(const half8*)&hlds[fragbase + (kt << 9)];
            half8 a1 = *(const half8*)&hlds[fragbase + ((kt + 1) << 9)];
            acc0 = MFMA16(a0, bfrag[16 + kt],     acc0);
            acc1 = MFMA16(a1, bfrag[16 + kt + 1], acc1);
        }
        floatx4 acc = acc0 + acc1;

        // ---- 5. gate exchange through LDS ----
        {
            const int ccol = lane & 15;
            const int crow = (lane >> 4) << 2;
#pragma unroll
            for (int v = 0; v < 4; ++v)
                gatebuf[wave * 272 + (crow + v) * 17 + ccol] = acc[v];
        }

        // ---- 6. w23: handed out-stores (t-1, rows 0-7); cvt x_{t+1} -> LDS ----
        if (wave >= 2) {
            if (t > 0) {
                float hvp = houts[(t - 1) & 1][lt];
                out[(size_t)(row0 + (lt >> 4)) * (TT * HH) + (size_t)(t - 1) * HH
                    + (cg << 4) + (lt & 15)] = hvp;
            }
            if (havex) {
                _Float16* xd = xbuf[(t + 1) & 1];
                half4 hc;
#pragma unroll
                for (int j = 0; j < 16; ++j) {
                    float4 v = xvv[j];
                    hc.x = (_Float16)v.x; hc.y = (_Float16)v.y;
                    hc.z = (_Float16)v.z; hc.w = (_Float16)v.w;
                    int c = xc8 + (j << 3);             // float4 slot
                    *(half4*)&xd[foff(xr, c << 2)] = hc;
                }
            }
        }
        barrier_lgkm();   // B: gatebuf + xbuf[(t+1)&1] ready

        // ---- 7. epilogue (all threads): cell math; tagged h-store ----
        {
            const int gidx = tr * 17 + tc;
            float ai = gatebuf[0 * 272 + gidx] + bi;
            float af = gatebuf[1 * 272 + gidx] + bf;
            float ao = gatebuf[2 * 272 + gidx] + bo;
            float ag = gatebuf[3 * 272 + gidx] + bg;
            float ig = 1.f / (1.f + __expf(-ai));
            float fg = 1.f / (1.f + __expf(-af));
            float og = 1.f / (1.f + __expf(-ao));
            float gg = 2.f / (1.f + __expf(-2.f * ag)) - 1.f;   // tanh
            c_state = fg * c_state + ig * gg;
            float hv = og * (2.f / (1.f + __expf(-2.f * c_state)) - 1.f);

            float pn = __shfl_down(hv, 1);
            if ((tc & 1) == 0) {
                _Float16 f0 = (_Float16)hv, f1 = (_Float16)pn;
                u16 b0, b1;
                __builtin_memcpy(&b0, &f0, 2); __builtin_memcpy(&b1, &f1, 2);
                const u32 wtag = 0xB000u | ((u32)((t + 1) >> 1) & 1u);
                u32 lo = ((u32)b0 << 16) | wtag;
                u32 hi = ((u32)b1 << 16) | wtag;
                u64 v = (u64)lo | ((u64)hi << 32);
                __hip_atomic_store(hq + (size_t)((t + 1) & 1) * (NBHH / 2)
                                   + (size_t)gn * 256 + (gh >> 1), v, AQ, SC);
            }
            // out: w01 hand over via LDS (w23 stores next step); w23 direct.
            if (wave < 2) houts[t & 1][tid] = hv;
            else out[(size_t)gn * (TT * HH) + (size_t)t * HH + gh] = hv;
        }
        // no barrier here: houts(t) read at t+1 after A; gatebuf rewritten
        // at t+1 after A; hlds restaged pre-A(t+1), readers done pre-B(t).
    }

    // ---- tail: flush handed rows for t = TT-1 ----
    barrier_lgkm();
    if (wave >= 2) {
        float hvp = houts[(TT - 1) & 1][lt];
        out[(size_t)(row0 + (lt >> 4)) * (TT * HH) + (size_t)(TT - 1) * HH
            + (cg << 4) + (lt & 15)] = hvp;
    }
}

extern "C" void kernel_launch(void* const* d_in, const int* in_sizes, int n_in,
                              void* d_out, int out_size, void* d_ws, size_t ws_size,
                              hipStream_t stream) {
    const float* x  = (const float*)d_in[0];
    const float* h0 = (const float*)d_in[1];
    const float* Wx = (const float*)d_in[2];
    const float* Wh = (const float*)d_in[3];
    const float* b  = (const float*)d_in[4];
    float* out = (float*)d_out;

    u64* hq = (u64*)d_ws;   // 2 slots x 64 x 512 x u32 = 256 KB

    init_ws_kernel<<<128, 256, 0, stream>>>(hq);
    lstm_persist<<<dim3(128), dim3(256), 0, stream>>>(x, h0, Wx, Wh, b, out, hq);
}